// Round 3
// baseline (516.455 us; speedup 1.0000x reference)
//
#include <hip/hip_runtime.h>
#include <math.h>

#define Cc 1000
#define Cpad 1024
#define Dd 256
#define Bb 16384
#define NSs 200000
#define MOM 0.1f
#define EPSV 1e-12f
#define EPSC 0.10f
#define CANDCAP 48
#define LISTCAP 40
#define NEG_BIG (-3.4e38f)
#define IDX_BIG 0x7fffffff

// d_out layout (floats), concat of reference return tuple
#define OUT_CENTER 0
#define OUT_SRC (Cc*Dd)                       // 256000
#define OUT_C2C (OUT_SRC + (size_t)NSs*Dd)    // 51,456,000
#define OUT_INTER (OUT_C2C + Cc*2)            // 51,458,000

// scratch inside out_src region (float offsets); consumed before k_src overwrites
#define SCR_FB 0                               // ushort[Bb*Dd]        (2,097,152 floats)
#define SCR_CB 2097152                         // ushort[Cpad*Dd]      (131,072 floats)
#define SCR_PART 2228224                       // float4[Bb*16]        (1,048,576 floats)
#define SCR_CAND 3276800                       // float2[Bb*CANDCAP]   (1,572,864 floats)
#define SCR_CNT 4849664                        // int[Bb]
// end ~4.87M floats << 51.2M region

// ws layout (floats) — total ~1.85 MB (within proven ws_size)
#define WS_CHAT 0
#define WS_INVF 256000
#define WS_MARK 272384                         // int[NSs]

typedef __bf16 bf16x8 __attribute__((ext_vector_type(8)));
typedef float  f32x4  __attribute__((ext_vector_type(4)));

__device__ __forceinline__ ushort f2bf(float f) {
    uint u = __float_as_uint(f);
    u += 0x7FFFu + ((u >> 16) & 1u);   // round-to-nearest-even
    return (ushort)(u >> 16);
}

__device__ __forceinline__ void upd_top2(float& s1, int& i1, float& s2, int& i2,
                                         float s, int i) {
    // jax.lax.top_k tie semantics: larger value first; equal values -> lower index first
    if (s > s1 || (s == s1 && i < i1)) {
        s2 = s1; i2 = i1; s1 = s; i1 = i;
    } else if (s > s2 || (s == s2 && i < i2)) {
        s2 = s; i2 = i;
    }
}

// ---------------- K_init: base copies (inter, c2c, center) + mark=-1 + cnt=0 ----------------
#define N_INTER4 (Cc*Cc*2/4)     // 500000
#define N_C2C4   (Cc*2/4)        // 500
#define N_CM4    (Cc*Dd/4)       // 64000
#define N_MARK4  (NSs/4)         // 50000
#define N_CNT4   (Bb/4)          // 4096
#define N_INIT4  (N_INTER4 + N_C2C4 + N_CM4 + N_MARK4 + N_CNT4)

__global__ void k_init(const float4* __restrict__ interdist,
                       const float4* __restrict__ c2c,
                       const float4* __restrict__ cmem,
                       float4* __restrict__ out_inter,
                       float4* __restrict__ out_c2c,
                       float4* __restrict__ out_center,
                       int4* __restrict__ mark, int4* __restrict__ cnt) {
    int i = blockIdx.x * blockDim.x + threadIdx.x;
    if (i < N_INTER4) {
        out_inter[i] = interdist[i];
    } else if (i < N_INTER4 + N_C2C4) {
        out_c2c[i - N_INTER4] = c2c[i - N_INTER4];
    } else if (i < N_INTER4 + N_C2C4 + N_CM4) {
        out_center[i - N_INTER4 - N_C2C4] = cmem[i - N_INTER4 - N_C2C4];
    } else if (i < N_INTER4 + N_C2C4 + N_CM4 + N_MARK4) {
        int4 m; m.x = -1; m.y = -1; m.z = -1; m.w = -1;
        mark[i - N_INTER4 - N_C2C4 - N_CM4] = m;
    } else if (i < N_INIT4) {
        int4 z; z.x = 0; z.y = 0; z.z = 0; z.w = 0;
        cnt[i - N_INTER4 - N_C2C4 - N_CM4 - N_MARK4] = z;
    }
}

// ---------------- K_scatter: mark[index[i]] = i ----------------
__global__ void k_scatter(const int* __restrict__ index, int* __restrict__ mark) {
    int i = blockIdx.x * blockDim.x + threadIdx.x;
    if (i < Bb) mark[index[i]] = i;
}

// ---------------- K1a: per-row norms, d1@label -> c2c, seg-sum atomics, feat->bf16 ----------------
__global__ void k_rows_a(const float* __restrict__ feat, const float* __restrict__ cmem,
                         const int* __restrict__ label,
                         float* __restrict__ out_center, float* __restrict__ out_c2c,
                         float* __restrict__ ws_invf, ushort* __restrict__ fb) {
    int wid  = threadIdx.x >> 6;
    int lane = threadIdx.x & 63;
    int row  = blockIdx.x * 4 + wid;
    if (row >= Bb) return;

    const float4 f4 = *(const float4*)(feat + (size_t)row * Dd + lane * 4);
    int lab = label[row];
    const float4 c4 = *(const float4*)(cmem + (size_t)lab * Dd + lane * 4);

    ushort4 h;
    h.x = f2bf(f4.x); h.y = f2bf(f4.y); h.z = f2bf(f4.z); h.w = f2bf(f4.w);
    *(ushort4*)(fb + (size_t)row * Dd + lane * 4) = h;

    float fs = f4.x*f4.x + f4.y*f4.y + f4.z*f4.z + f4.w*f4.w;
    float dt = f4.x*c4.x + f4.y*c4.y + f4.z*c4.z + f4.w*c4.w;
    float cs = c4.x*c4.x + c4.y*c4.y + c4.z*c4.z + c4.w*c4.w;
    #pragma unroll
    for (int off = 32; off; off >>= 1) {
        fs += __shfl_xor(fs, off);
        dt += __shfl_xor(dt, off);
        cs += __shfl_xor(cs, off);
    }
    float invf = 1.0f / fmaxf(sqrtf(fs), EPSV);
    if (lane == 0) {
        ws_invf[row] = invf;
        float invc = 1.0f / fmaxf(sqrtf(cs), EPSV);
        float d1 = 0.5f * (1.0f - dt * invf * invc);
        atomicAdd(out_c2c + lab * 2,     1.0f);
        atomicAdd(out_c2c + lab * 2 + 1, d1);
    }
    atomicAdd(out_center + (size_t)lab * Dd + lane * 4 + 0, f4.x);
    atomicAdd(out_center + (size_t)lab * Dd + lane * 4 + 1, f4.y);
    atomicAdd(out_center + (size_t)lab * Dd + lane * 4 + 2, f4.z);
    atomicAdd(out_center + (size_t)lab * Dd + lane * 4 + 3, f4.w);
}

// ---------------- K2: normalize center_new -> chat (f32) + chat_bf16 (padded to 1024) ----------------
__global__ void k_chat(const float* __restrict__ out_center, float* __restrict__ chat,
                       ushort* __restrict__ cb) {
    int c = blockIdx.x;      // 0..1023
    int lane = threadIdx.x;  // 64
    if (c >= Cc) {
        ushort4 z; z.x = 0; z.y = 0; z.z = 0; z.w = 0;
        *(ushort4*)(cb + (size_t)c * Dd + lane * 4) = z;
        return;
    }
    float4 v = *(const float4*)(out_center + (size_t)c * Dd + lane * 4);
    float ss = v.x*v.x + v.y*v.y + v.z*v.z + v.w*v.w;
    #pragma unroll
    for (int off = 32; off; off >>= 1) ss += __shfl_xor(ss, off);
    float inv = 1.0f / fmaxf(sqrtf(ss), EPSV);
    float4 r; r.x = v.x*inv; r.y = v.y*inv; r.z = v.z*inv; r.w = v.w*inv;
    *(float4*)(chat + (size_t)c * Dd + lane * 4) = r;
    ushort4 h;
    h.x = f2bf(r.x); h.y = f2bf(r.y); h.z = f2bf(r.z); h.w = f2bf(r.w);
    *(ushort4*)(cb + (size_t)c * Dd + lane * 4) = h;
}

// ---------------- K4: fused bf16 MFMA GEMM + per-tile top-2 + extra-candidate emission ----------------
// Wave tile 64 rows x 64 cols; lane holds acc[mi][ni][r] for row=mi*16+kg*4+r, col=c0+ni*16+rl.
__global__ __launch_bounds__(256) void k_gemm(const ushort* __restrict__ fb,
                                              const ushort* __restrict__ cb,
                                              float4* __restrict__ part,
                                              float2* __restrict__ cand,
                                              int* __restrict__ cnt) {
    int wid  = threadIdx.x >> 6;
    int lane = threadIdx.x & 63;
    int rl = lane & 15;
    int kg = lane >> 4;
    int row0 = blockIdx.y * 64;
    int c0   = blockIdx.x * 256 + wid * 64;
    int tile = blockIdx.x * 4 + wid;

    const ushort* fp = fb + (size_t)(row0 + rl) * Dd + kg * 8;
    const ushort* cp = cb + (size_t)(c0  + rl) * Dd + kg * 8;

    f32x4 acc[4][4];
    f32x4 z = {0.f, 0.f, 0.f, 0.f};
    #pragma unroll
    for (int mi = 0; mi < 4; mi++)
        #pragma unroll
        for (int ni = 0; ni < 4; ni++)
            acc[mi][ni] = z;

    #pragma unroll
    for (int ks = 0; ks < 8; ks++) {
        bf16x8 a[4], b[4];
        #pragma unroll
        for (int mi = 0; mi < 4; mi++)
            a[mi] = *(const bf16x8*)(fp + (size_t)mi * 16 * Dd + ks * 32);
        #pragma unroll
        for (int ni = 0; ni < 4; ni++)
            b[ni] = *(const bf16x8*)(cp + (size_t)ni * 16 * Dd + ks * 32);
        #pragma unroll
        for (int mi = 0; mi < 4; mi++)
            #pragma unroll
            for (int ni = 0; ni < 4; ni++)
                acc[mi][ni] = __builtin_amdgcn_mfma_f32_16x16x32_bf16(a[mi], b[ni], acc[mi][ni], 0, 0, 0);
    }

    // ---- per-lane top2 per row-slot j=mi*4+r over its 4 cols (static indexing only) ----
    float S1[16], S2[16];
    int   I1[16], I2[16];
    #pragma unroll
    for (int j = 0; j < 16; j++) { S1[j] = NEG_BIG; S2[j] = NEG_BIG; I1[j] = IDX_BIG; I2[j] = IDX_BIG; }
    #pragma unroll
    for (int mi = 0; mi < 4; mi++)
        #pragma unroll
        for (int r = 0; r < 4; r++)
            #pragma unroll
            for (int ni = 0; ni < 4; ni++) {
                int col = c0 + ni * 16 + rl;
                if (col < Cc)
                    upd_top2(S1[mi*4+r], I1[mi*4+r], S2[mi*4+r], I2[mi*4+r], acc[mi][ni][r], col);
            }
    // ---- butterfly across the 16-lane rl group (disjoint col sets -> no dupes) ----
    #pragma unroll
    for (int off = 1; off < 16; off <<= 1)
        #pragma unroll
        for (int j = 0; j < 16; j++) {
            float t1 = __shfl_xor(S1[j], off), t2 = __shfl_xor(S2[j], off);
            int   u1 = __shfl_xor(I1[j], off), u2 = __shfl_xor(I2[j], off);
            upd_top2(S1[j], I1[j], S2[j], I2[j], t1, u1);
            upd_top2(S1[j], I1[j], S2[j], I2[j], t2, u2);
        }
    // ---- emit rare extras: within EPSC of tile-2nd-max, not the tile top2 ----
    #pragma unroll
    for (int mi = 0; mi < 4; mi++)
        #pragma unroll
        for (int r = 0; r < 4; r++)
            #pragma unroll
            for (int ni = 0; ni < 4; ni++) {
                int col = c0 + ni * 16 + rl;
                float v = acc[mi][ni][r];
                int j = mi*4 + r;
                if (col < Cc && v >= S2[j] - EPSC && col != I1[j] && col != I2[j]) {
                    int row = row0 + mi * 16 + kg * 4 + r;
                    int slot = atomicAdd(cnt + row, 1);
                    if (slot < CANDCAP)
                        cand[(size_t)row * CANDCAP + slot] = make_float2(v, __int_as_float(col));
                }
            }
    // ---- write per-tile top2 partials (lane rl==j owns row-slot j; static index) ----
    #pragma unroll
    for (int j = 0; j < 16; j++) {
        if (rl == j) {
            int row = row0 + (j >> 2) * 16 + kg * 4 + (j & 3);
            part[(size_t)row * 16 + tile] =
                make_float4(S1[j], S2[j], __int_as_float(I1[j]), __int_as_float(I2[j]));
        }
    }
}

// ---------------- K5: merge 16 tile partials, filter by global s2-EPSC, f32 rescore ----------------
__global__ __launch_bounds__(256) void k_fin(const float4* __restrict__ part,
                                             const float2* __restrict__ cand,
                                             const int* __restrict__ cnt,
                                             const float* __restrict__ feat,
                                             const float* __restrict__ chat,
                                             const float* __restrict__ ws_invf,
                                             float* __restrict__ out_inter) {
    __shared__ int lcnt[4];
    __shared__ int lst[4][LISTCAP];
    int wid  = threadIdx.x >> 6;
    int lane = threadIdx.x & 63;
    int row  = blockIdx.x * 4 + wid;
    if (lane == 0) lcnt[wid] = 0;

    float4 p;
    if (lane < 16) p = part[(size_t)row * 16 + lane];
    else p = make_float4(NEG_BIG, NEG_BIG, __int_as_float(IDX_BIG), __int_as_float(IDX_BIG));

    float s1 = p.x, s2 = p.y;
    int   i1 = __float_as_int(p.z), i2 = __float_as_int(p.w);
    #pragma unroll
    for (int off = 1; off < 64; off <<= 1) {
        float t1 = __shfl_xor(s1, off), t2 = __shfl_xor(s2, off);
        int   u1 = __shfl_xor(i1, off), u2 = __shfl_xor(i2, off);
        upd_top2(s1, i1, s2, i2, t1, u1);
        upd_top2(s1, i1, s2, i2, t2, u2);
    }
    float thr = s2 - EPSC;
    // collect rescore set: partial pairs >= thr
    if (lane < 16) {
        if (p.x >= thr) { int s = atomicAdd(&lcnt[wid], 1); if (s < LISTCAP) lst[wid][s] = __float_as_int(p.z); }
        if (p.y >= thr) { int s = atomicAdd(&lcnt[wid], 1); if (s < LISTCAP) lst[wid][s] = __float_as_int(p.w); }
    }
    // plus extras from cand list
    int n = cnt[row]; if (n > CANDCAP) n = CANDCAP;
    if (lane < n) {
        float2 cv = cand[(size_t)row * CANDCAP + lane];
        if (cv.x >= thr) { int s = atomicAdd(&lcnt[wid], 1); if (s < LISTCAP) lst[wid][s] = __float_as_int(cv.y); }
    }
    __syncthreads();
    int m = lcnt[wid]; if (m > LISTCAP) m = LISTCAP;

    const float4 f4 = *(const float4*)(feat + (size_t)row * Dd + lane * 4);
    float F1 = NEG_BIG, F2 = NEG_BIG;
    int   J1 = IDX_BIG, J2 = IDX_BIG;
    for (int k = 0; k < m; k++) {
        int col = lst[wid][k];
        const float4 c4 = *(const float4*)(chat + (size_t)col * Dd + lane * 4);
        float d = f4.x*c4.x + f4.y*c4.y + f4.z*c4.z + f4.w*c4.w;
        #pragma unroll
        for (int off = 32; off; off >>= 1) d += __shfl_xor(d, off);
        upd_top2(F1, J1, F2, J2, d, col);   // order-independent
    }
    if (lane == 0) {
        float inter = 0.5f * ws_invf[row] * (F1 - F2);
        size_t off2 = ((size_t)J1 * Cc + J2) * 2;
        atomicAdd(out_inter + off2,     1.0f);
        atomicAdd(out_inter + off2 + 1, inter);
    }
}

// ---------------- K3: single-pass source_mem copy/lerp ----------------
__global__ void k_src(const float4* __restrict__ src, const float4* __restrict__ feat,
                      const int* __restrict__ mark, float4* __restrict__ dst) {
    const int n4 = NSs * Dd / 4;   // 12,800,000
    int stride = gridDim.x * blockDim.x;
    for (int e = blockIdx.x * blockDim.x + threadIdx.x; e < n4; e += stride) {
        int row = e >> 6;            // Dd/4 = 64 float4 per row; wave-uniform
        int m = mark[row];
        float4 v = src[e];
        if (m >= 0) {
            float4 f = feat[(size_t)m * 64 + (e & 63)];
            v.x = (1.0f - MOM) * v.x + MOM * f.x;
            v.y = (1.0f - MOM) * v.y + MOM * f.y;
            v.z = (1.0f - MOM) * v.z + MOM * f.z;
            v.w = (1.0f - MOM) * v.w + MOM * f.w;
        }
        dst[e] = v;
    }
}

extern "C" void kernel_launch(void* const* d_in, const int* in_sizes, int n_in,
                              void* d_out, int out_size, void* d_ws, size_t ws_size,
                              hipStream_t stream) {
    const float* feat   = (const float*)d_in[0];
    const float* cmem   = (const float*)d_in[1];
    const float* smem   = (const float*)d_in[2];
    const float* c2c    = (const float*)d_in[3];
    const float* inter  = (const float*)d_in[4];
    const int*   label  = (const int*)d_in[5];
    const int*   index  = (const int*)d_in[6];

    float* out = (float*)d_out;
    float* out_center = out + OUT_CENTER;
    float* out_src    = out + OUT_SRC;
    float* out_c2c    = out + OUT_C2C;
    float* out_inter  = out + OUT_INTER;

    float* ws    = (float*)d_ws;
    float* chat  = ws + WS_CHAT;
    float* winvf = ws + WS_INVF;
    int*   mark  = (int*)(ws + WS_MARK);

    // scratch inside out_src region (consumed before k_src overwrites)
    ushort* fb    = (ushort*)(out_src + SCR_FB);
    ushort* cb    = (ushort*)(out_src + SCR_CB);
    float4* part  = (float4*)(out_src + SCR_PART);
    float2* cand  = (float2*)(out_src + SCR_CAND);
    int*    cnt   = (int*)(out_src + SCR_CNT);

    // 1) base copies + mark/cnt init
    k_init<<<(N_INIT4 + 255) / 256, 256, 0, stream>>>(
        (const float4*)inter, (const float4*)c2c, (const float4*)cmem,
        (float4*)out_inter, (float4*)out_c2c, (float4*)out_center,
        (int4*)mark, (int4*)cnt);
    // 2) scatter index -> mark
    k_scatter<<<Bb / 256, 256, 0, stream>>>(index, mark);
    // 3) per-row norms, c2c, center atomics, feat->bf16
    k_rows_a<<<Bb / 4, 256, 0, stream>>>(feat, cmem, label, out_center, out_c2c, winvf, fb);
    // 4) normalize center_new -> chat + chat_bf16 (padded)
    k_chat<<<Cpad, 64, 0, stream>>>(out_center, chat, cb);
    // 5) fused MFMA GEMM + tile top2 + extras
    {
        dim3 grid(4, Bb / 64);
        k_gemm<<<grid, 256, 0, stream>>>(fb, cb, part, cand, cnt);
    }
    // 6) merge + f32 rescore -> interdist atomics (before scratch is overwritten)
    k_fin<<<Bb / 4, 256, 0, stream>>>(part, cand, cnt, feat, chat, winvf, out_inter);
    // 7) single-pass source_mem copy/lerp (overwrites scratch region)
    k_src<<<4096, 256, 0, stream>>>((const float4*)smem, (const float4*)feat, mark,
                                    (float4*)out_src);
}

// Round 4
// 452.829 us; speedup vs baseline: 1.1405x; 1.1405x over previous
//
#include <hip/hip_runtime.h>
#include <math.h>

#define Cc 1000
#define Cpad 1024
#define Dd 256
#define Bb 16384
#define NSs 200000
#define MOM 0.1f
#define EPSV 1e-12f
#define EPSC 0.10f
#define CANDCAP 48
#define LISTCAP 40
#define NEG_BIG (-3.4e38f)
#define IDX_BIG 0x7fffffff

// d_out layout (floats), concat of reference return tuple
#define OUT_CENTER 0
#define OUT_SRC (Cc*Dd)                       // 256000
#define OUT_C2C (OUT_SRC + (size_t)NSs*Dd)    // 51,456,000
#define OUT_INTER (OUT_C2C + Cc*2)            // 51,458,000

// scratch inside out_src region (float offsets); consumed before k_src overwrites
#define SCR_FB 0                               // ushort[Bb*Dd]        (2,097,152 floats)
#define SCR_CB 2097152                         // ushort[Cpad*Dd]      (131,072 floats)
#define SCR_PART 2228224                       // float4[Bb*16]        (1,048,576 floats)
#define SCR_CAND 3276800                       // float2[Bb*CANDCAP]   (1,572,864 floats)
#define SCR_CNT 4849664                        // int[Bb]
// end ~4.87M floats << 51.2M region

// ws layout (floats) — total ~1.85 MB
#define WS_CHAT 0
#define WS_INVF 256000
#define WS_MARK 272384                         // int[NSs]

typedef __bf16 bf16x8 __attribute__((ext_vector_type(8)));
typedef float  f32x4  __attribute__((ext_vector_type(4)));

__device__ __forceinline__ ushort f2bf(float f) {
    uint u = __float_as_uint(f);
    u += 0x7FFFu + ((u >> 16) & 1u);   // round-to-nearest-even
    return (ushort)(u >> 16);
}

__device__ __forceinline__ void upd_top2(float& s1, int& i1, float& s2, int& i2,
                                         float s, int i) {
    // jax.lax.top_k tie semantics: larger value first; equal values -> lower index first
    if (s > s1 || (s == s1 && i < i1)) {
        s2 = s1; i2 = i1; s1 = s; i1 = i;
    } else if (s > s2 || (s == s2 && i < i2)) {
        s2 = s; i2 = i;
    }
}

// ---------------- K_init: base copies (inter, c2c, center) + mark=-1 + cnt=0 ----------------
#define N_INTER4 (Cc*Cc*2/4)     // 500000
#define N_C2C4   (Cc*2/4)        // 500
#define N_CM4    (Cc*Dd/4)       // 64000
#define N_MARK4  (NSs/4)         // 50000
#define N_CNT4   (Bb/4)          // 4096
#define N_INIT4  (N_INTER4 + N_C2C4 + N_CM4 + N_MARK4 + N_CNT4)

__global__ void k_init(const float4* __restrict__ interdist,
                       const float4* __restrict__ c2c,
                       const float4* __restrict__ cmem,
                       float4* __restrict__ out_inter,
                       float4* __restrict__ out_c2c,
                       float4* __restrict__ out_center,
                       int4* __restrict__ mark, int4* __restrict__ cnt) {
    int i = blockIdx.x * blockDim.x + threadIdx.x;
    if (i < N_INTER4) {
        out_inter[i] = interdist[i];
    } else if (i < N_INTER4 + N_C2C4) {
        out_c2c[i - N_INTER4] = c2c[i - N_INTER4];
    } else if (i < N_INTER4 + N_C2C4 + N_CM4) {
        out_center[i - N_INTER4 - N_C2C4] = cmem[i - N_INTER4 - N_C2C4];
    } else if (i < N_INTER4 + N_C2C4 + N_CM4 + N_MARK4) {
        int4 m; m.x = -1; m.y = -1; m.z = -1; m.w = -1;
        mark[i - N_INTER4 - N_C2C4 - N_CM4] = m;
    } else if (i < N_INIT4) {
        int4 z; z.x = 0; z.y = 0; z.z = 0; z.w = 0;
        cnt[i - N_INTER4 - N_C2C4 - N_CM4 - N_MARK4] = z;
    }
}

// ---------------- K_scatter: mark[index[i]] = i ----------------
__global__ void k_scatter(const int* __restrict__ index, int* __restrict__ mark) {
    int i = blockIdx.x * blockDim.x + threadIdx.x;
    if (i < Bb) mark[index[i]] = i;
}

// ---------------- K1a: per-row norms, d1@label -> c2c, seg-sum atomics, feat->bf16 ----------------
__global__ void k_rows_a(const float* __restrict__ feat, const float* __restrict__ cmem,
                         const int* __restrict__ label,
                         float* __restrict__ out_center, float* __restrict__ out_c2c,
                         float* __restrict__ ws_invf, ushort* __restrict__ fb) {
    int wid  = threadIdx.x >> 6;
    int lane = threadIdx.x & 63;
    int row  = blockIdx.x * 4 + wid;
    if (row >= Bb) return;

    const float4 f4 = *(const float4*)(feat + (size_t)row * Dd + lane * 4);
    int lab = label[row];
    const float4 c4 = *(const float4*)(cmem + (size_t)lab * Dd + lane * 4);

    ushort4 h;
    h.x = f2bf(f4.x); h.y = f2bf(f4.y); h.z = f2bf(f4.z); h.w = f2bf(f4.w);
    *(ushort4*)(fb + (size_t)row * Dd + lane * 4) = h;

    float fs = f4.x*f4.x + f4.y*f4.y + f4.z*f4.z + f4.w*f4.w;
    float dt = f4.x*c4.x + f4.y*c4.y + f4.z*c4.z + f4.w*c4.w;
    float cs = c4.x*c4.x + c4.y*c4.y + c4.z*c4.z + c4.w*c4.w;
    #pragma unroll
    for (int off = 32; off; off >>= 1) {
        fs += __shfl_xor(fs, off);
        dt += __shfl_xor(dt, off);
        cs += __shfl_xor(cs, off);
    }
    float invf = 1.0f / fmaxf(sqrtf(fs), EPSV);
    if (lane == 0) {
        ws_invf[row] = invf;
        float invc = 1.0f / fmaxf(sqrtf(cs), EPSV);
        float d1 = 0.5f * (1.0f - dt * invf * invc);
        atomicAdd(out_c2c + lab * 2,     1.0f);
        atomicAdd(out_c2c + lab * 2 + 1, d1);
    }
    atomicAdd(out_center + (size_t)lab * Dd + lane * 4 + 0, f4.x);
    atomicAdd(out_center + (size_t)lab * Dd + lane * 4 + 1, f4.y);
    atomicAdd(out_center + (size_t)lab * Dd + lane * 4 + 2, f4.z);
    atomicAdd(out_center + (size_t)lab * Dd + lane * 4 + 3, f4.w);
}

// ---------------- K2: normalize center_new -> chat (f32) + chat_bf16 (padded to 1024) ----------------
__global__ void k_chat(const float* __restrict__ out_center, float* __restrict__ chat,
                       ushort* __restrict__ cb) {
    int c = blockIdx.x;      // 0..1023
    int lane = threadIdx.x;  // 64
    if (c >= Cc) {
        ushort4 z; z.x = 0; z.y = 0; z.z = 0; z.w = 0;
        *(ushort4*)(cb + (size_t)c * Dd + lane * 4) = z;
        return;
    }
    float4 v = *(const float4*)(out_center + (size_t)c * Dd + lane * 4);
    float ss = v.x*v.x + v.y*v.y + v.z*v.z + v.w*v.w;
    #pragma unroll
    for (int off = 32; off; off >>= 1) ss += __shfl_xor(ss, off);
    float inv = 1.0f / fmaxf(sqrtf(ss), EPSV);
    float4 r; r.x = v.x*inv; r.y = v.y*inv; r.z = v.z*inv; r.w = v.w*inv;
    *(float4*)(chat + (size_t)c * Dd + lane * 4) = r;
    ushort4 h;
    h.x = f2bf(r.x); h.y = f2bf(r.y); h.z = f2bf(r.z); h.w = f2bf(r.w);
    *(ushort4*)(cb + (size_t)c * Dd + lane * 4) = h;
}

// ---------------- K4: fused bf16 MFMA GEMM + per-tile top-2, register-bounded ----------------
// Wave tile 64 rows x 64 cols; lane holds acc[mi][ni][r] for row=row0+mi*16+kg*4+r,
// col=c0+ni*16+rl. Reduction processes one mi (16 rows) at a time so only 16 extra
// regs are live beside the 64-reg accumulator (R3 spilled: 386MB scratch writes).
__global__ __launch_bounds__(256, 2) void k_gemm(const ushort* __restrict__ fb,
                                                 const ushort* __restrict__ cb,
                                                 float4* __restrict__ part,
                                                 float2* __restrict__ cand,
                                                 int* __restrict__ cnt) {
    int wid  = threadIdx.x >> 6;
    int lane = threadIdx.x & 63;
    int rl = lane & 15;
    int kg = lane >> 4;
    int row0 = blockIdx.y * 64;
    int c0   = blockIdx.x * 256 + wid * 64;
    int tile = blockIdx.x * 4 + wid;

    const ushort* fp = fb + (size_t)(row0 + rl) * Dd + kg * 8;
    const ushort* cp = cb + (size_t)(c0  + rl) * Dd + kg * 8;

    f32x4 acc[4][4];
    f32x4 z = {0.f, 0.f, 0.f, 0.f};
    #pragma unroll
    for (int mi = 0; mi < 4; mi++)
        #pragma unroll
        for (int ni = 0; ni < 4; ni++)
            acc[mi][ni] = z;

    #pragma unroll
    for (int ks = 0; ks < 8; ks++) {
        bf16x8 a[4], b[4];
        #pragma unroll
        for (int mi = 0; mi < 4; mi++)
            a[mi] = *(const bf16x8*)(fp + (size_t)mi * 16 * Dd + ks * 32);
        #pragma unroll
        for (int ni = 0; ni < 4; ni++)
            b[ni] = *(const bf16x8*)(cp + (size_t)ni * 16 * Dd + ks * 32);
        #pragma unroll
        for (int mi = 0; mi < 4; mi++)
            #pragma unroll
            for (int ni = 0; ni < 4; ni++)
                acc[mi][ni] = __builtin_amdgcn_mfma_f32_16x16x32_bf16(a[mi], b[ni], acc[mi][ni], 0, 0, 0);
    }

    // ---- reduction: one mi row-group (16 rows) at a time ----
    #pragma unroll
    for (int mi = 0; mi < 4; mi++) {
        float S1[4], S2[4];
        int   I1[4], I2[4];
        #pragma unroll
        for (int r = 0; r < 4; r++) { S1[r] = NEG_BIG; S2[r] = NEG_BIG; I1[r] = IDX_BIG; I2[r] = IDX_BIG; }
        // per-lane top2 over this lane's 4 cols, per row-slot r
        #pragma unroll
        for (int ni = 0; ni < 4; ni++) {
            int col = c0 + ni * 16 + rl;
            if (col < Cc) {
                #pragma unroll
                for (int r = 0; r < 4; r++)
                    upd_top2(S1[r], I1[r], S2[r], I2[r], acc[mi][ni][r], col);
            }
        }
        // butterfly across the 16-lane rl group (disjoint col sets -> no dupes)
        #pragma unroll
        for (int off = 1; off < 16; off <<= 1) {
            #pragma unroll
            for (int r = 0; r < 4; r++) {
                float t1 = __shfl_xor(S1[r], off), t2 = __shfl_xor(S2[r], off);
                int   u1 = __shfl_xor(I1[r], off), u2 = __shfl_xor(I2[r], off);
                upd_top2(S1[r], I1[r], S2[r], I2[r], t1, u1);
                upd_top2(S1[r], I1[r], S2[r], I2[r], t2, u2);
            }
        }
        // emit rare extras: within EPSC of tile-2nd-max, not the tile top2
        #pragma unroll
        for (int ni = 0; ni < 4; ni++) {
            int col = c0 + ni * 16 + rl;
            #pragma unroll
            for (int r = 0; r < 4; r++) {
                float v = acc[mi][ni][r];
                if (col < Cc && v >= S2[r] - EPSC && col != I1[r] && col != I2[r]) {
                    int row = row0 + mi * 16 + kg * 4 + r;
                    int slot = atomicAdd(cnt + row, 1);
                    if (slot < CANDCAP)
                        cand[(size_t)row * CANDCAP + slot] = make_float2(v, __int_as_float(col));
                }
            }
        }
        // per-tile top2 partials: lane rl==r writes row-slot r (static index)
        #pragma unroll
        for (int r = 0; r < 4; r++) {
            if (rl == r) {
                int row = row0 + mi * 16 + kg * 4 + r;
                part[(size_t)row * 16 + tile] =
                    make_float4(S1[r], S2[r], __int_as_float(I1[r]), __int_as_float(I2[r]));
            }
        }
    }
}

// ---------------- K5: merge 16 tile partials, filter by global s2-EPSC, f32 rescore ----------------
__global__ __launch_bounds__(256) void k_fin(const float4* __restrict__ part,
                                             const float2* __restrict__ cand,
                                             const int* __restrict__ cnt,
                                             const float* __restrict__ feat,
                                             const float* __restrict__ chat,
                                             const float* __restrict__ ws_invf,
                                             float* __restrict__ out_inter) {
    __shared__ int lcnt[4];
    __shared__ int lst[4][LISTCAP];
    int wid  = threadIdx.x >> 6;
    int lane = threadIdx.x & 63;
    int row  = blockIdx.x * 4 + wid;
    if (lane == 0) lcnt[wid] = 0;

    float4 p;
    if (lane < 16) p = part[(size_t)row * 16 + lane];
    else p = make_float4(NEG_BIG, NEG_BIG, __int_as_float(IDX_BIG), __int_as_float(IDX_BIG));

    float s1 = p.x, s2 = p.y;
    int   i1 = __float_as_int(p.z), i2 = __float_as_int(p.w);
    #pragma unroll
    for (int off = 1; off < 64; off <<= 1) {
        float t1 = __shfl_xor(s1, off), t2 = __shfl_xor(s2, off);
        int   u1 = __shfl_xor(i1, off), u2 = __shfl_xor(i2, off);
        upd_top2(s1, i1, s2, i2, t1, u1);
        upd_top2(s1, i1, s2, i2, t2, u2);
    }
    float thr = s2 - EPSC;
    if (lane < 16) {
        if (p.x >= thr) { int s = atomicAdd(&lcnt[wid], 1); if (s < LISTCAP) lst[wid][s] = __float_as_int(p.z); }
        if (p.y >= thr) { int s = atomicAdd(&lcnt[wid], 1); if (s < LISTCAP) lst[wid][s] = __float_as_int(p.w); }
    }
    int n = cnt[row]; if (n > CANDCAP) n = CANDCAP;
    if (lane < n) {
        float2 cv = cand[(size_t)row * CANDCAP + lane];
        if (cv.x >= thr) { int s = atomicAdd(&lcnt[wid], 1); if (s < LISTCAP) lst[wid][s] = __float_as_int(cv.y); }
    }
    __syncthreads();
    int m = lcnt[wid]; if (m > LISTCAP) m = LISTCAP;

    const float4 f4 = *(const float4*)(feat + (size_t)row * Dd + lane * 4);
    float F1 = NEG_BIG, F2 = NEG_BIG;
    int   J1 = IDX_BIG, J2 = IDX_BIG;
    for (int k = 0; k < m; k++) {
        int col = lst[wid][k];
        const float4 c4 = *(const float4*)(chat + (size_t)col * Dd + lane * 4);
        float d = f4.x*c4.x + f4.y*c4.y + f4.z*c4.z + f4.w*c4.w;
        #pragma unroll
        for (int off = 32; off; off >>= 1) d += __shfl_xor(d, off);
        upd_top2(F1, J1, F2, J2, d, col);   // order-independent
    }
    if (lane == 0) {
        float inter = 0.5f * ws_invf[row] * (F1 - F2);
        size_t off2 = ((size_t)J1 * Cc + J2) * 2;
        atomicAdd(out_inter + off2,     1.0f);
        atomicAdd(out_inter + off2 + 1, inter);
    }
}

// ---------------- K3: single-pass source_mem copy/lerp ----------------
__global__ void k_src(const float4* __restrict__ src, const float4* __restrict__ feat,
                      const int* __restrict__ mark, float4* __restrict__ dst) {
    const int n4 = NSs * Dd / 4;   // 12,800,000
    int stride = gridDim.x * blockDim.x;
    for (int e = blockIdx.x * blockDim.x + threadIdx.x; e < n4; e += stride) {
        int row = e >> 6;            // Dd/4 = 64 float4 per row
        int m = mark[row];
        float4 v = src[e];
        if (m >= 0) {
            float4 f = feat[(size_t)m * 64 + (e & 63)];
            v.x = (1.0f - MOM) * v.x + MOM * f.x;
            v.y = (1.0f - MOM) * v.y + MOM * f.y;
            v.z = (1.0f - MOM) * v.z + MOM * f.z;
            v.w = (1.0f - MOM) * v.w + MOM * f.w;
        }
        dst[e] = v;
    }
}

extern "C" void kernel_launch(void* const* d_in, const int* in_sizes, int n_in,
                              void* d_out, int out_size, void* d_ws, size_t ws_size,
                              hipStream_t stream) {
    const float* feat   = (const float*)d_in[0];
    const float* cmem   = (const float*)d_in[1];
    const float* smem   = (const float*)d_in[2];
    const float* c2c    = (const float*)d_in[3];
    const float* inter  = (const float*)d_in[4];
    const int*   label  = (const int*)d_in[5];
    const int*   index  = (const int*)d_in[6];

    float* out = (float*)d_out;
    float* out_center = out + OUT_CENTER;
    float* out_src    = out + OUT_SRC;
    float* out_c2c    = out + OUT_C2C;
    float* out_inter  = out + OUT_INTER;

    float* ws    = (float*)d_ws;
    float* chat  = ws + WS_CHAT;
    float* winvf = ws + WS_INVF;
    int*   mark  = (int*)(ws + WS_MARK);

    // scratch inside out_src region (consumed before k_src overwrites)
    ushort* fb    = (ushort*)(out_src + SCR_FB);
    ushort* cb    = (ushort*)(out_src + SCR_CB);
    float4* part  = (float4*)(out_src + SCR_PART);
    float2* cand  = (float2*)(out_src + SCR_CAND);
    int*    cnt   = (int*)(out_src + SCR_CNT);

    // 1) base copies + mark/cnt init
    k_init<<<(N_INIT4 + 255) / 256, 256, 0, stream>>>(
        (const float4*)inter, (const float4*)c2c, (const float4*)cmem,
        (float4*)out_inter, (float4*)out_c2c, (float4*)out_center,
        (int4*)mark, (int4*)cnt);
    // 2) scatter index -> mark
    k_scatter<<<Bb / 256, 256, 0, stream>>>(index, mark);
    // 3) per-row norms, c2c, center atomics, feat->bf16
    k_rows_a<<<Bb / 4, 256, 0, stream>>>(feat, cmem, label, out_center, out_c2c, winvf, fb);
    // 4) normalize center_new -> chat + chat_bf16 (padded)
    k_chat<<<Cpad, 64, 0, stream>>>(out_center, chat, cb);
    // 5) fused MFMA GEMM + tile top2 + extras
    {
        dim3 grid(4, Bb / 64);
        k_gemm<<<grid, 256, 0, stream>>>(fb, cb, part, cand, cnt);
    }
    // 6) merge + f32 rescore -> interdist atomics (before scratch is overwritten)
    k_fin<<<Bb / 4, 256, 0, stream>>>(part, cand, cnt, feat, chat, winvf, out_inter);
    // 7) single-pass source_mem copy/lerp (overwrites scratch region)
    k_src<<<4096, 256, 0, stream>>>((const float4*)smem, (const float4*)feat, mark,
                                    (float4*)out_src);
}

// Round 6
// 269.513 us; speedup vs baseline: 1.9163x; 1.6802x over previous
//
#include <hip/hip_runtime.h>
#include <math.h>

#define Cc 1000
#define Cpad 1024
#define Dd 256
#define Bb 16384
#define NSs 200000
#define MOM 0.1f
#define EPSV 1e-12f
#define EPSC 0.10f
#define NEG_BIG (-3.4e38f)
#define IDX_BIG 0x7fffffff

// d_out layout (floats), concat of reference return tuple
#define OUT_CENTER 0
#define OUT_SRC (Cc*Dd)                       // 256000
#define OUT_C2C (OUT_SRC + (size_t)NSs*Dd)    // 51,456,000
#define OUT_INTER (OUT_C2C + Cc*2)            // 51,458,000

// scratch inside out_src region (float offsets); consumed before k_src overwrites
#define SCR_SCORES 0                           // float[Bb*Cpad] = 16,777,216 floats
#define SCR_FB ((size_t)Bb * Cpad)             // ushort[Bb*Dd]   (2,097,152 floats)
#define SCR_CB (SCR_FB + (size_t)Bb*Dd/2)      // ushort[Cpad*Dd] (131,072 floats)
// end ~19.0M floats << 51.2M region

// ws layout (floats) — total ~1.85 MB
#define WS_CHAT 0
#define WS_INVF 256000
#define WS_MARK 272384                         // int[NSs]

typedef __bf16 bf16x8 __attribute__((ext_vector_type(8)));
typedef float  f32x4  __attribute__((ext_vector_type(4)));

__device__ __forceinline__ ushort f2bf(float f) {
    uint u = __float_as_uint(f);
    u += 0x7FFFu + ((u >> 16) & 1u);   // round-to-nearest-even
    return (ushort)(u >> 16);
}

__device__ __forceinline__ void gload16(const void* g, void* l) {
    __builtin_amdgcn_global_load_lds(
        (const __attribute__((address_space(1))) void*)g,
        (__attribute__((address_space(3))) void*)l, 16, 0, 0);
}

__device__ __forceinline__ void upd_top2(float& s1, int& i1, float& s2, int& i2,
                                         float s, int i) {
    // jax.lax.top_k tie semantics: larger value first; equal values -> lower index first
    if (s > s1 || (s == s1 && i < i1)) {
        s2 = s1; i2 = i1; s1 = s; i1 = i;
    } else if (s > s2 || (s == s2 && i < i2)) {
        s2 = s; i2 = i;
    }
}

// ---------------- K_init: base copies (inter, c2c, center) + mark=-1 ----------------
#define N_INTER4 (Cc*Cc*2/4)     // 500000
#define N_C2C4   (Cc*2/4)        // 500
#define N_CM4    (Cc*Dd/4)       // 64000
#define N_MARK4  (NSs/4)         // 50000
#define N_INIT4  (N_INTER4 + N_C2C4 + N_CM4 + N_MARK4)

__global__ void k_init(const float4* __restrict__ interdist,
                       const float4* __restrict__ c2c,
                       const float4* __restrict__ cmem,
                       float4* __restrict__ out_inter,
                       float4* __restrict__ out_c2c,
                       float4* __restrict__ out_center,
                       int4* __restrict__ mark) {
    int i = blockIdx.x * blockDim.x + threadIdx.x;
    if (i < N_INTER4) {
        out_inter[i] = interdist[i];
    } else if (i < N_INTER4 + N_C2C4) {
        out_c2c[i - N_INTER4] = c2c[i - N_INTER4];
    } else if (i < N_INTER4 + N_C2C4 + N_CM4) {
        out_center[i - N_INTER4 - N_C2C4] = cmem[i - N_INTER4 - N_C2C4];
    } else if (i < N_INIT4) {
        int4 m; m.x = -1; m.y = -1; m.z = -1; m.w = -1;
        mark[i - N_INTER4 - N_C2C4 - N_CM4] = m;
    }
}

// ---------------- K_scatter: mark[index[i]] = i ----------------
__global__ void k_scatter(const int* __restrict__ index, int* __restrict__ mark) {
    int i = blockIdx.x * blockDim.x + threadIdx.x;
    if (i < Bb) mark[index[i]] = i;
}

// ---------------- K1a: per-row norms, d1@label -> c2c, seg-sum atomics, feat->bf16 ----------------
__global__ void k_rows_a(const float* __restrict__ feat, const float* __restrict__ cmem,
                         const int* __restrict__ label,
                         float* __restrict__ out_center, float* __restrict__ out_c2c,
                         float* __restrict__ ws_invf, ushort* __restrict__ fb) {
    int wid  = threadIdx.x >> 6;
    int lane = threadIdx.x & 63;
    int row  = blockIdx.x * 4 + wid;
    if (row >= Bb) return;

    const float4 f4 = *(const float4*)(feat + (size_t)row * Dd + lane * 4);
    int lab = label[row];
    const float4 c4 = *(const float4*)(cmem + (size_t)lab * Dd + lane * 4);

    ushort4 h;
    h.x = f2bf(f4.x); h.y = f2bf(f4.y); h.z = f2bf(f4.z); h.w = f2bf(f4.w);
    *(ushort4*)(fb + (size_t)row * Dd + lane * 4) = h;

    float fs = f4.x*f4.x + f4.y*f4.y + f4.z*f4.z + f4.w*f4.w;
    float dt = f4.x*c4.x + f4.y*c4.y + f4.z*c4.z + f4.w*c4.w;
    float cs = c4.x*c4.x + c4.y*c4.y + c4.z*c4.z + c4.w*c4.w;
    #pragma unroll
    for (int off = 32; off; off >>= 1) {
        fs += __shfl_xor(fs, off);
        dt += __shfl_xor(dt, off);
        cs += __shfl_xor(cs, off);
    }
    float invf = 1.0f / fmaxf(sqrtf(fs), EPSV);
    if (lane == 0) {
        ws_invf[row] = invf;
        float invc = 1.0f / fmaxf(sqrtf(cs), EPSV);
        float d1 = 0.5f * (1.0f - dt * invf * invc);
        atomicAdd(out_c2c + lab * 2,     1.0f);
        atomicAdd(out_c2c + lab * 2 + 1, d1);
    }
    atomicAdd(out_center + (size_t)lab * Dd + lane * 4 + 0, f4.x);
    atomicAdd(out_center + (size_t)lab * Dd + lane * 4 + 1, f4.y);
    atomicAdd(out_center + (size_t)lab * Dd + lane * 4 + 2, f4.z);
    atomicAdd(out_center + (size_t)lab * Dd + lane * 4 + 3, f4.w);
}

// ---------------- K2: normalize center_new -> chat (f32) + chat_bf16 (padded to 1024) ----------------
__global__ void k_chat(const float* __restrict__ out_center, float* __restrict__ chat,
                       ushort* __restrict__ cb) {
    int c = blockIdx.x;      // 0..1023
    int lane = threadIdx.x;  // 64
    if (c >= Cc) {
        ushort4 z; z.x = 0; z.y = 0; z.z = 0; z.w = 0;
        *(ushort4*)(cb + (size_t)c * Dd + lane * 4) = z;
        return;
    }
    float4 v = *(const float4*)(out_center + (size_t)c * Dd + lane * 4);
    float ss = v.x*v.x + v.y*v.y + v.z*v.z + v.w*v.w;
    #pragma unroll
    for (int off = 32; off; off >>= 1) ss += __shfl_xor(ss, off);
    float inv = 1.0f / fmaxf(sqrtf(ss), EPSV);
    float4 r; r.x = v.x*inv; r.y = v.y*inv; r.z = v.z*inv; r.w = v.w*inv;
    *(float4*)(chat + (size_t)c * Dd + lane * 4) = r;
    ushort4 h;
    h.x = f2bf(r.x); h.y = f2bf(r.y); h.z = f2bf(r.z); h.w = f2bf(r.w);
    *(ushort4*)(cb + (size_t)c * Dd + lane * 4) = h;
}

// ---------------- K4: LDS-staged bf16 MFMA GEMM (m97-style), scores f32 out ----------------
// Block tile 128 rows x 128 cols, BK=64, 4 waves each owning a 64x64 quadrant.
// LDS A/B tiles are row-major [128][64] bf16 (128 B/row) with T2 XOR swizzle
// (chunk ^= row&7, chunk = 16B unit) applied via PRE-SWIZZLED GLOBAL SOURCE
// (linear LDS dest, rule 21), read back with the same XOR -> ~2-way conflicts (free).
// R5 BUG FIX: fb/cb rows are 256 ushorts = 512 BYTES; R5 used byte stride 256
// (half a row) so the GEMM contracted wrong data -> interdist failed. Row
// addressing now stays in ushort units; only intra-row offsets are bytes.
__global__ __launch_bounds__(256, 2) void k_gemm(const ushort* __restrict__ fb,
                                                 const ushort* __restrict__ cb,
                                                 float* __restrict__ scores) {
    __shared__ __align__(16) char Asb[128 * 128];   // 16 KB
    __shared__ __align__(16) char Bsb[128 * 128];   // 16 KB

    int tid  = threadIdx.x;
    int wid  = tid >> 6;
    int lane = tid & 63;
    int rl = lane & 15;
    int kg = lane >> 4;
    int wr = wid >> 1;          // 0..1 row half
    int wc = wid & 1;           // 0..1 col half
    int row0 = blockIdx.y * 128;
    int c0   = blockIdx.x * 128;

    // pre-swizzled source chunk: lane writes physical chunk (lane&7) of LDS row
    // rloc+(lane>>3); it must fetch logical chunk (lane&7)^(lane>>3)
    int realb = ((lane & 7) ^ (lane >> 3)) << 4;    // byte offset within 128B row

    f32x4 acc[4][4];
    f32x4 z = {0.f, 0.f, 0.f, 0.f};
    #pragma unroll
    for (int mi = 0; mi < 4; mi++)
        #pragma unroll
        for (int ni = 0; ni < 4; ni++)
            acc[mi][ni] = z;

    for (int t = 0; t < 4; t++) {           // K steps of 64
        // ---- stage: each wave loads 32 rows of A and of B (4 issues each, 8 rows/issue)
        #pragma unroll
        for (int i = 0; i < 4; i++) {
            int rloc = wid * 32 + i * 8;    // multiple of 8 -> (rloc&7)==0
            int grow = row0 + rloc + (lane >> 3);
            gload16((const char*)(fb + (size_t)grow * Dd) + t * 128 + realb,
                    Asb + rloc * 128);
        }
        #pragma unroll
        for (int i = 0; i < 4; i++) {
            int rloc = wid * 32 + i * 8;
            int gcol = c0 + rloc + (lane >> 3);
            gload16((const char*)(cb + (size_t)gcol * Dd) + t * 128 + realb,
                    Bsb + rloc * 128);
        }
        asm volatile("s_waitcnt vmcnt(0)" ::: "memory");
        __syncthreads();

        // ---- fragments: swizzled ds_read_b128
        bf16x8 a[4][2], b[4][2];
        #pragma unroll
        for (int mi = 0; mi < 4; mi++)
            #pragma unroll
            for (int ks = 0; ks < 2; ks++) {
                int r = wr * 64 + mi * 16 + rl;
                int off = r * 128 + ((ks * 64 + kg * 16) ^ ((r & 7) << 4));
                a[mi][ks] = *(const bf16x8*)(Asb + off);
            }
        #pragma unroll
        for (int ni = 0; ni < 4; ni++)
            #pragma unroll
            for (int ks = 0; ks < 2; ks++) {
                int r = wc * 64 + ni * 16 + rl;
                int off = r * 128 + ((ks * 64 + kg * 16) ^ ((r & 7) << 4));
                b[ni][ks] = *(const bf16x8*)(Bsb + off);
            }

        // ---- 32 MFMAs
        #pragma unroll
        for (int ks = 0; ks < 2; ks++)
            #pragma unroll
            for (int mi = 0; mi < 4; mi++)
                #pragma unroll
                for (int ni = 0; ni < 4; ni++)
                    acc[mi][ni] = __builtin_amdgcn_mfma_f32_16x16x32_bf16(
                        a[mi][ks], b[ni][ks], acc[mi][ni], 0, 0, 0);

        __syncthreads();   // before next stage overwrites LDS
    }

    // ---- epilogue: C/D layout col=lane&15, row=(lane>>4)*4+reg [m89]
    #pragma unroll
    for (int mi = 0; mi < 4; mi++) {
        int row = row0 + wr * 64 + mi * 16 + kg * 4;
        #pragma unroll
        for (int ni = 0; ni < 4; ni++) {
            int col = c0 + wc * 64 + ni * 16 + rl;
            #pragma unroll
            for (int rr = 0; rr < 4; rr++)
                scores[(size_t)(row + rr) * Cpad + col] = acc[mi][ni][rr];
        }
    }
}

// ---------------- K5: per-row exact top-2 of approx scores + f32 rescore of near-top candidates ----------------
__global__ __launch_bounds__(256) void k_sel(const float* __restrict__ scores,
                                             const float* __restrict__ feat,
                                             const float* __restrict__ chat,
                                             const float* __restrict__ ws_invf,
                                             float* __restrict__ out_inter) {
    __shared__ int cnt[4];
    __shared__ int clist[4][32];
    int wid  = threadIdx.x >> 6;
    int lane = threadIdx.x & 63;
    int row  = blockIdx.x * 4 + wid;
    if (lane == 0) cnt[wid] = 0;

    const float4* sp = (const float4*)(scores + (size_t)row * Cpad);
    float v[16];
    float s1 = NEG_BIG, s2 = NEG_BIG;
    int   i1 = IDX_BIG, i2 = IDX_BIG;
    #pragma unroll
    for (int j = 0; j < 4; j++) {
        float4 q = sp[j * 64 + lane];           // cols j*256 + lane*4 .. +3 (coalesced)
        int cbase = j * 256 + lane * 4;
        v[j*4+0] = q.x; v[j*4+1] = q.y; v[j*4+2] = q.z; v[j*4+3] = q.w;
        if (cbase + 0 < Cc) upd_top2(s1, i1, s2, i2, q.x, cbase + 0);
        if (cbase + 1 < Cc) upd_top2(s1, i1, s2, i2, q.y, cbase + 1);
        if (cbase + 2 < Cc) upd_top2(s1, i1, s2, i2, q.z, cbase + 2);
        if (cbase + 3 < Cc) upd_top2(s1, i1, s2, i2, q.w, cbase + 3);
    }
    // butterfly merge (disjoint column sets per lane -> no duplicate insertions)
    #pragma unroll
    for (int off = 1; off < 64; off <<= 1) {
        float ps1 = __shfl_xor(s1, off), ps2 = __shfl_xor(s2, off);
        int   pi1 = __shfl_xor(i1, off), pi2 = __shfl_xor(i2, off);
        upd_top2(s1, i1, s2, i2, ps1, pi1);
        upd_top2(s1, i1, s2, i2, ps2, pi2);
    }
    // candidates: every col with approx score within EPSC of the 2nd max
    float thr = s2 - EPSC;
    #pragma unroll
    for (int j = 0; j < 16; j++) {
        int c = (j >> 2) * 256 + lane * 4 + (j & 3);
        if (v[j] >= thr && c < Cc) {
            int slot = atomicAdd(&cnt[wid], 1);
            if (slot < 32) clist[wid][slot] = c;
        }
    }
    __syncthreads();
    int n = cnt[wid]; if (n > 32) n = 32;

    const float4 f4 = *(const float4*)(feat + (size_t)row * Dd + lane * 4);
    float S1 = NEG_BIG, S2 = NEG_BIG;
    int   I1 = IDX_BIG, I2 = IDX_BIG;
    for (int k = 0; k < n; k++) {
        int c = clist[wid][k];
        const float4 c4 = *(const float4*)(chat + (size_t)c * Dd + lane * 4);
        float d = f4.x*c4.x + f4.y*c4.y + f4.z*c4.z + f4.w*c4.w;
        #pragma unroll
        for (int off = 32; off; off >>= 1) d += __shfl_xor(d, off);
        upd_top2(S1, I1, S2, I2, d, c);   // order-independent result
    }
    if (lane == 0) {
        float inter = 0.5f * ws_invf[row] * (S1 - S2);
        size_t off2 = ((size_t)I1 * Cc + I2) * 2;
        atomicAdd(out_inter + off2,     1.0f);
        atomicAdd(out_inter + off2 + 1, inter);
    }
}

// ---------------- K3: single-pass source_mem copy/lerp ----------------
__global__ void k_src(const float4* __restrict__ src, const float4* __restrict__ feat,
                      const int* __restrict__ mark, float4* __restrict__ dst) {
    const int n4 = NSs * Dd / 4;   // 12,800,000
    int stride = gridDim.x * blockDim.x;
    for (int e = blockIdx.x * blockDim.x + threadIdx.x; e < n4; e += stride) {
        int row = e >> 6;            // Dd/4 = 64 float4 per row
        int m = mark[row];
        float4 v = src[e];
        if (m >= 0) {
            float4 f = feat[(size_t)m * 64 + (e & 63)];
            v.x = (1.0f - MOM) * v.x + MOM * f.x;
            v.y = (1.0f - MOM) * v.y + MOM * f.y;
            v.z = (1.0f - MOM) * v.z + MOM * f.z;
            v.w = (1.0f - MOM) * v.w + MOM * f.w;
        }
        dst[e] = v;
    }
}

extern "C" void kernel_launch(void* const* d_in, const int* in_sizes, int n_in,
                              void* d_out, int out_size, void* d_ws, size_t ws_size,
                              hipStream_t stream) {
    const float* feat   = (const float*)d_in[0];
    const float* cmem   = (const float*)d_in[1];
    const float* smem   = (const float*)d_in[2];
    const float* c2c    = (const float*)d_in[3];
    const float* inter  = (const float*)d_in[4];
    const int*   label  = (const int*)d_in[5];
    const int*   index  = (const int*)d_in[6];

    float* out = (float*)d_out;
    float* out_center = out + OUT_CENTER;
    float* out_src    = out + OUT_SRC;
    float* out_c2c    = out + OUT_C2C;
    float* out_inter  = out + OUT_INTER;

    float* ws    = (float*)d_ws;
    float* chat  = ws + WS_CHAT;
    float* winvf = ws + WS_INVF;
    int*   mark  = (int*)(ws + WS_MARK);

    // scratch inside out_src region (consumed before k_src overwrites)
    float*  scores = out_src + SCR_SCORES;
    ushort* fb     = (ushort*)(out_src + SCR_FB);
    ushort* cb     = (ushort*)(out_src + SCR_CB);

    // 1) base copies + mark init
    k_init<<<(N_INIT4 + 255) / 256, 256, 0, stream>>>(
        (const float4*)inter, (const float4*)c2c, (const float4*)cmem,
        (float4*)out_inter, (float4*)out_c2c, (float4*)out_center,
        (int4*)mark);
    // 2) scatter index -> mark
    k_scatter<<<Bb / 256, 256, 0, stream>>>(index, mark);
    // 3) per-row norms, c2c, center atomics, feat->bf16
    k_rows_a<<<Bb / 4, 256, 0, stream>>>(feat, cmem, label, out_center, out_c2c, winvf, fb);
    // 4) normalize center_new -> chat + chat_bf16 (padded)
    k_chat<<<Cpad, 64, 0, stream>>>(out_center, chat, cb);
    // 5) LDS-staged MFMA GEMM -> scores
    {
        dim3 grid(Cpad / 128, Bb / 128);   // (8, 128)
        k_gemm<<<grid, 256, 0, stream>>>(fb, cb, scores);
    }
    // 6) top-2 + f32 rescore -> interdist atomics (before scratch is overwritten)
    k_sel<<<Bb / 4, 256, 0, stream>>>(scores, feat, chat, winvf, out_inter);
    // 7) single-pass source_mem copy/lerp (overwrites scratch region)
    k_src<<<4096, 256, 0, stream>>>((const float4*)smem, (const float4*)feat, mark,
                                    (float4*)out_src);
}